// Round 5
// baseline (268.126 us; speedup 1.0000x reference)
//
#include <hip/hip_runtime.h>

#define B   2
#define C   256
#define CM  64     // compressed channels
#define CE  100    // encoder out channels
#define H   40
#define W   40
#define HW  1600
#define KK  25     // K*K

#define NBLK 400u

// Manual grid barrier (graph-capture-friendly). Capacity: LDS 44.8 KB ->
// 3 blocks/CU -> 768 co-resident slots >= 400 (even at 2 blocks/CU: 512),
// so every block is resident and the spin cannot deadlock. Agent-scope
// release/acquire gives cross-XCD L2 writeback/invalidate (Guideline 16).
__device__ __forceinline__ void grid_barrier(unsigned* cnt) {
  __syncthreads();
  if (threadIdx.x == 0) {
    __hip_atomic_fetch_add(cnt, 1u, __ATOMIC_RELEASE, __HIP_MEMORY_SCOPE_AGENT);
    while (__hip_atomic_load(cnt, __ATOMIC_ACQUIRE, __HIP_MEMORY_SCOPE_AGENT) <
           NBLK)
      __builtin_amdgcn_s_sleep(2);
  }
  __syncthreads();
}

// ---------------------------------------------------------------------------
// Single persistent kernel, 400 blocks x 256 threads, 44.8 KB LDS.
// Phase 0 (937 vblocks, grid-stride):
//   vb   0..199 : 1x1 conv 256->64 LDS GEMM -> pc
//   vb 200..711 : zero-pad x -> xpad[b][c][44][48]
//   vb 712..936 : transpose w_enc -> wT
// barrier
// Phase 1 (800 vblocks): 3x3 conv 64->100 -> encP (scalar-load weights)
// barrier
// Phase 2 (800 vblocks): fused softmax + reassembly -> out
// All phase bodies identical to the round-3 (passing, 103.9 us) kernels.
// ---------------------------------------------------------------------------
__global__ __launch_bounds__(256) void k_all(
    const float* __restrict__ x, const float* __restrict__ w_comp,
    const float* __restrict__ w_enc, float* __restrict__ pc,
    float* __restrict__ encP, float* __restrict__ wT,
    float* __restrict__ xpad, float* __restrict__ out,
    unsigned* __restrict__ bars) {
  __shared__ __align__(16) float smem[11200];    // 44.8 KB
  const int bid = blockIdx.x;
  const int tid = threadIdx.x;

  // ======================= Phase 0: prep + 1x1 conv ========================
  for (int vb = bid; vb < 937; vb += NBLK) {
    if (vb >= 712) {                     // ---- weight transpose (57600 elems)
      int idx = (vb - 712) * 256 + tid;
      if (idx < 57600) {
        int row = idx / 576, col = idx - row * 576;  // col=(icq*16+icl)*9+tap
        int ocq = row / 25, ol = row - ocq * 25;
        wT[((size_t)(ocq * 576 + col)) * 32 + ol] = w_enc[idx];
      }
    } else if (vb >= 200) {              // ---- pad one (b,c) plane of x
      const int plane = vb - 200;        // 0..511
      const float* src = x + (size_t)plane * HW;
      float* dst = xpad + (size_t)plane * (44 * 48);
      for (int i = tid; i < 44 * 48; i += 256) {
        int py = i / 48, px = i - py * 48;
        int gy = py - 2, gx = px - 2;
        float v = 0.f;
        if (gy >= 0 && gy < H && gx >= 0 && gx < W) v = src[gy * W + gx];
        dst[i] = v;
      }
    } else {                             // ---- 1x1 conv GEMM (vb 0..199)
      const int t = vb % 25, ich = (vb / 25) & 3, b = vb / 100;
      float* xs  = smem;                 // 4096 floats [icl][px]
      float* wsA = smem + 4096;          // 4096 floats [icl][oc]

      const float4* x4 =
          (const float4*)(x + ((size_t)b * C + ich * 64) * HW + t * 64);
#pragma unroll
      for (int i = 0; i < 4; i++) {
        int idx = tid + i * 256;         // icl = idx>>4, q = idx&15
        ((float4*)xs)[idx] = x4[(idx >> 4) * 400 + (idx & 15)];
      }
      const float4* w4 = (const float4*)w_comp;
#pragma unroll
      for (int i = 0; i < 4; i++) {
        int idx = tid + i * 256;
        int icq = idx >> 6, oc = idx & 63;
        float4 f = w4[oc * 64 + ich * 16 + icq];
        wsA[(icq * 4 + 0) * 64 + oc] = f.x;
        wsA[(icq * 4 + 1) * 64 + oc] = f.y;
        wsA[(icq * 4 + 2) * 64 + oc] = f.z;
        wsA[(icq * 4 + 3) * 64 + oc] = f.w;
      }
      __syncthreads();

      const int ty = tid >> 4, tx = tid & 15;
      float acc[4][4];
#pragma unroll
      for (int i = 0; i < 4; i++)
#pragma unroll
        for (int j = 0; j < 4; j++) acc[i][j] = 0.f;

#pragma unroll 4
      for (int icl = 0; icl < 64; icl++) {
        float4 a = *(const float4*)&wsA[icl * 64 + ty * 4];
        float4 bb = *(const float4*)&xs[icl * 64 + tx * 4];
        float av[4] = {a.x, a.y, a.z, a.w};
        float bv[4] = {bb.x, bb.y, bb.z, bb.w};
#pragma unroll
        for (int i = 0; i < 4; i++)
#pragma unroll
          for (int j = 0; j < 4; j++) acc[i][j] += av[i] * bv[j];
      }

      float* o = pc + ((size_t)ich * B + b) * CM * HW + t * 64 + tx * 4;
#pragma unroll
      for (int j = 0; j < 4; j++)
        *(float4*)&o[(size_t)(ty * 4 + j) * HW] =
            make_float4(acc[j][0], acc[j][1], acc[j][2], acc[j][3]);
    }
  }

  grid_barrier(&bars[0]);

  // ======================= Phase 1: 3x3 conv ===============================
  for (int vb = bid; vb < 800; vb += NBLK) {
    __syncthreads();                     // protect smem across iterations
    const int t = vb % 50, ocq = (vb / 50) % 4, icq = vb / 200;
    const int ty = t / 10, tx = t - ty * 10;   // tile origin (ty*8, tx*4)
    float* cs   = smem;                  // 1920 floats [bb2][icl16][10*6]
    float* pacc = smem;                  // alias for reduction (3200 floats)

    for (int i = tid; i < 1920; i += 256) {
      int bb = i / 960, r = i - bb * 960;
      int icl = r / 60, rr = r - icl * 60;
      int yy = rr / 6, xx = rr - yy * 6;
      int gy = ty * 8 + yy - 1, gx = tx * 4 + xx - 1;
      float v = 0.f;
      if (gy >= 0 && gy < H && gx >= 0 && gx < W) {
        int o = bb * 102400 + (icq * 16 + icl) * HW + gy * W + gx;
        v = pc[o] + pc[204800 + o] + pc[409600 + o] + pc[614400 + o];
      }
      cs[i] = v;
    }
    __syncthreads();

    const int wv = tid >> 6, lane = tid & 63;
    const int bb = lane >> 5, py = (lane & 31) >> 2, px = lane & 3;
    float acc[25];
#pragma unroll
    for (int j = 0; j < 25; j++) acc[j] = 0.f;

    const float* wbase0 = wT + (size_t)((ocq * 4 + icq) * 16) * 288;  // *9*32

#pragma unroll
    for (int t4 = 0; t4 < 4; t4++) {
      const int icl = __builtin_amdgcn_readfirstlane(wv * 4 + t4);
      const float* c0 = &cs[(bb * 16 + icl) * 60 + py * 6 + px];
      const float* wrow = wbase0 + icl * 288;
#pragma unroll
      for (int dy = 0; dy < 3; dy++)
#pragma unroll
        for (int dx = 0; dx < 3; dx++) {
          const float xv = c0[dy * 6 + dx];
          const float* wq = wrow + (dy * 3 + dx) * 32;
#pragma unroll
          for (int j = 0; j < 25; j++) acc[j] = fmaf(xv, wq[j], acc[j]);
        }
    }

    __syncthreads();
    if (wv == 1 || wv == 3) {
      const int slot = wv >> 1;
#pragma unroll
      for (int j = 0; j < 25; j++) pacc[(slot * 25 + j) * 64 + lane] = acc[j];
    }
    __syncthreads();
    if (wv == 0 || wv == 2) {
      const int slot = wv >> 1;
#pragma unroll
      for (int j = 0; j < 25; j++) acc[j] += pacc[(slot * 25 + j) * 64 + lane];
    }
    __syncthreads();
    if (wv == 2) {
#pragma unroll
      for (int j = 0; j < 25; j++) pacc[j * 64 + lane] = acc[j];
    }
    __syncthreads();
    if (wv == 0) {
      const int base_px = (ty * 8 + py) * W + tx * 4 + px;
#pragma unroll
      for (int ol = 0; ol < 25; ol++)
        encP[(((size_t)icq * 2 + bb) * CE + ocq * 25 + ol) * HW + base_px] =
            acc[ol] + pacc[ol * 64 + lane];
    }
  }

  grid_barrier(&bars[1]);

  // ======================= Phase 2: softmax + reassembly ===================
  for (int vb = bid; vb < 800; vb += NBLK) {
    __syncthreads();                     // protect smem across iterations
    const int i0 = vb % 40, jq = (vb / 40) % 10, b = vb / 400;
    float* xsm  = smem;                  // 10400 floats [px][ch stride 260]
    float* sv   = smem + 10400;          // 400 raw logits [k*16 + v]
    float* wlds = smem + 10800;          // 400 normalized [j0l*100+k*4+d]

    // ---- (a) softmax partial sums, coalesced
    const int t20 = (jq >= 5) ? 1 : 0;
    if (tid < 200) {
      const float* eb = encP + (size_t)b * 160000 + i0 * 40;
#pragma unroll
      for (int u = 0; u < 2; u++) {
        const int p = tid * 2 + u;       // p = k*16 + v
        const int k = p >> 4, v = p & 15;
        const int j0l = v >> 2, d = v & 3;
        const int off = 2 * t20 + (d & 1);
        const int col = (jq * 4 + j0l - 20 * t20) * 2 + (d >> 1);
        const float* ep = eb + (size_t)(k * 4 + off) * 1600 + col;
        sv[p] = ep[0] + ep[320000] + ep[640000] + ep[960000];
      }
    }

    // ---- (b) x halo: 5 rows x 8 cols x 256 ch from padded x
    {
      const float* xb = xpad + (size_t)b * 256 * (44 * 48) + i0 * 48 + jq * 4;
      const int f4 = tid & 1, cth = tid >> 1;    // cth 0..127
#pragma unroll
      for (int it = 0; it < 10; it++) {
        const int ki = (it < 5) ? it : it - 5;
        const int c  = (it < 5 ? 0 : 128) + cth;
        float4 v = *(const float4*)(xb + ((size_t)c * 44 + ki) * 48 + f4 * 4);
        const int px = ki * 8 + f4 * 4;
        xsm[(px + 0) * 260 + c] = v.x;
        xsm[(px + 1) * 260 + c] = v.y;
        xsm[(px + 2) * 260 + c] = v.z;
        xsm[(px + 3) * 260 + c] = v.w;
      }
    }
    __syncthreads();

    // ---- (d) finish softmax: 16 threads, one (j0l,d) variant each
    if (tid < 16) {
      const int j0l = tid >> 2, d = tid & 3;
      float vk[KK];
      float m = -1e30f;
#pragma unroll
      for (int k = 0; k < KK; k++) {
        vk[k] = sv[k * 16 + tid];
        m = fmaxf(m, vk[k]);
      }
      float s = 0.f;
#pragma unroll
      for (int k = 0; k < KK; k++) {
        vk[k] = expf(vk[k] - m);
        s += vk[k];
      }
      const float inv = 1.f / s;
#pragma unroll
      for (int k = 0; k < KK; k++) wlds[j0l * 100 + k * 4 + d] = vk[k] * inv;
    }
    __syncthreads();

    // ---- (f) reassembly compute
    const int wv = tid >> 6, lane = tid & 63, ch0 = lane * 4;
    float4 a0 = make_float4(0.f, 0.f, 0.f, 0.f);
    float4 a1 = a0, a2 = a0, a3 = a0;

#pragma unroll
    for (int ki = 0; ki < 5; ki++)
#pragma unroll
      for (int kj = 0; kj < 5; kj++) {
        float4 xv = *(const float4*)&xsm[(ki * 8 + wv + kj) * 260 + ch0];
        float4 w4 = *(const float4*)&wlds[wv * 100 + (ki * 5 + kj) * 4];
        a0.x += xv.x * w4.x; a0.y += xv.y * w4.x; a0.z += xv.z * w4.x; a0.w += xv.w * w4.x;
        a1.x += xv.x * w4.y; a1.y += xv.y * w4.y; a1.z += xv.z * w4.y; a1.w += xv.w * w4.y;
        a2.x += xv.x * w4.z; a2.y += xv.y * w4.z; a2.z += xv.z * w4.z; a2.w += xv.w * w4.z;
        a3.x += xv.x * w4.w; a3.y += xv.y * w4.w; a3.z += xv.z * w4.w; a3.w += xv.w * w4.w;
      }

    const int j0 = jq * 4 + wv;
    float* ob = out + ((size_t)b * C + ch0) * 6400 + i0 * 160 + j0 * 4;
    *(float4*)&ob[0]     = make_float4(a0.x, a1.x, a2.x, a3.x);
    *(float4*)&ob[6400]  = make_float4(a0.y, a1.y, a2.y, a3.y);
    *(float4*)&ob[12800] = make_float4(a0.z, a1.z, a2.z, a3.z);
    *(float4*)&ob[19200] = make_float4(a0.w, a1.w, a2.w, a3.w);
  }
}

// ---------------------------------------------------------------------------
extern "C" void kernel_launch(void* const* d_in, const int* in_sizes, int n_in,
                              void* d_out, int out_size, void* d_ws, size_t ws_size,
                              hipStream_t stream) {
  const float* x      = (const float*)d_in[0];
  const float* w_comp = (const float*)d_in[1];
  const float* w_enc  = (const float*)d_in[2];
  float* out = (float*)d_out;

  float* pc       = (float*)d_ws;                      // 3,276,800 B
  float* encP     = (float*)((char*)d_ws + 3276800);   // 5,120,000 B
  float* wT       = (float*)((char*)d_ws + 8396800);   //   294,912 B
  float* xpad     = (float*)((char*)d_ws + 8691712);   // 4,325,376 B
  unsigned* bars  = (unsigned*)((char*)d_ws + 16000000);  // 2 counters

  // counters are poisoned by the harness each iteration -> re-zero (capturable)
  hipMemsetAsync(bars, 0, 2 * sizeof(unsigned), stream);

  k_all<<<dim3(NBLK), dim3(256), 0, stream>>>(x, w_comp, w_enc, pc, encP, wT,
                                              xpad, out, bars);
}

// Round 6
// 198.282 us; speedup vs baseline: 1.3522x; 1.3522x over previous
//
#include <hip/hip_runtime.h>

#define B   2
#define C   256
#define CM  64     // compressed channels
#define CE  100    // encoder out channels
#define H   40
#define W   40
#define HW  1600
#define KK  25     // K*K

#define NBLK 400u

// Manual grid barrier (graph-capture-friendly). Capacity: LDS 44.8 KB ->
// 3 blocks/CU -> 768 co-resident slots >= 400, so no deadlock.
// Protocol (round-5 post-mortem): NO acquire in the poll loop — a per-poll
// agent-acquire emits an L2 invalidate each iteration (invalidate storm,
// ~100 us/barrier measured). Instead: RELEASE on arrival, RELAXED RMW polls
// (RMW executes at the coherence point so it sees remote increments without
// cache maintenance), one ACQUIRE RMW on exit (single invalidate per block).
__device__ __forceinline__ void grid_barrier(unsigned* cnt) {
  __syncthreads();
  if (threadIdx.x == 0) {
    __hip_atomic_fetch_add(cnt, 1u, __ATOMIC_RELEASE, __HIP_MEMORY_SCOPE_AGENT);
    while (__hip_atomic_fetch_add(cnt, 0u, __ATOMIC_RELAXED,
                                  __HIP_MEMORY_SCOPE_AGENT) < NBLK)
      __builtin_amdgcn_s_sleep(8);
    __hip_atomic_fetch_add(cnt, 0u, __ATOMIC_ACQUIRE, __HIP_MEMORY_SCOPE_AGENT);
  }
  __syncthreads();
}

// ---------------------------------------------------------------------------
// Single persistent kernel, 400 blocks x 256 threads, 44.8 KB LDS.
// Phase 0 (937 vblocks, grid-stride):
//   vb   0..199 : 1x1 conv 256->64 LDS GEMM -> pc
//   vb 200..711 : zero-pad x -> xpad[b][c][44][48]
//   vb 712..936 : transpose w_enc -> wT
// barrier
// Phase 1 (800 vblocks): 3x3 conv 64->100 -> encP (scalar-load weights)
// barrier
// Phase 2 (800 vblocks): fused softmax + reassembly -> out
// Phase bodies identical to the round-3 (passing, 103.9 us) kernels.
// ---------------------------------------------------------------------------
__global__ __launch_bounds__(256) void k_all(
    const float* __restrict__ x, const float* __restrict__ w_comp,
    const float* __restrict__ w_enc, float* __restrict__ pc,
    float* __restrict__ encP, float* __restrict__ wT,
    float* __restrict__ xpad, float* __restrict__ out,
    unsigned* __restrict__ bars) {
  __shared__ __align__(16) float smem[11200];    // 44.8 KB
  const int bid = blockIdx.x;
  const int tid = threadIdx.x;

  // ======================= Phase 0: prep + 1x1 conv ========================
  for (int vb = bid; vb < 937; vb += NBLK) {
    if (vb >= 712) {                     // ---- weight transpose (57600 elems)
      int idx = (vb - 712) * 256 + tid;
      if (idx < 57600) {
        int row = idx / 576, col = idx - row * 576;  // col=(icq*16+icl)*9+tap
        int ocq = row / 25, ol = row - ocq * 25;
        wT[((size_t)(ocq * 576 + col)) * 32 + ol] = w_enc[idx];
      }
    } else if (vb >= 200) {              // ---- pad one (b,c) plane of x
      const int plane = vb - 200;        // 0..511
      const float* src = x + (size_t)plane * HW;
      float* dst = xpad + (size_t)plane * (44 * 48);
      for (int i = tid; i < 44 * 48; i += 256) {
        int py = i / 48, px = i - py * 48;
        int gy = py - 2, gx = px - 2;
        float v = 0.f;
        if (gy >= 0 && gy < H && gx >= 0 && gx < W) v = src[gy * W + gx];
        dst[i] = v;
      }
    } else {                             // ---- 1x1 conv GEMM (vb 0..199)
      const int t = vb % 25, ich = (vb / 25) & 3, b = vb / 100;
      float* xs  = smem;                 // 4096 floats [icl][px]
      float* wsA = smem + 4096;          // 4096 floats [icl][oc]

      const float4* x4 =
          (const float4*)(x + ((size_t)b * C + ich * 64) * HW + t * 64);
#pragma unroll
      for (int i = 0; i < 4; i++) {
        int idx = tid + i * 256;         // icl = idx>>4, q = idx&15
        ((float4*)xs)[idx] = x4[(idx >> 4) * 400 + (idx & 15)];
      }
      const float4* w4 = (const float4*)w_comp;
#pragma unroll
      for (int i = 0; i < 4; i++) {
        int idx = tid + i * 256;
        int icq = idx >> 6, oc = idx & 63;
        float4 f = w4[oc * 64 + ich * 16 + icq];
        wsA[(icq * 4 + 0) * 64 + oc] = f.x;
        wsA[(icq * 4 + 1) * 64 + oc] = f.y;
        wsA[(icq * 4 + 2) * 64 + oc] = f.z;
        wsA[(icq * 4 + 3) * 64 + oc] = f.w;
      }
      __syncthreads();

      const int ty = tid >> 4, tx = tid & 15;
      float acc[4][4];
#pragma unroll
      for (int i = 0; i < 4; i++)
#pragma unroll
        for (int j = 0; j < 4; j++) acc[i][j] = 0.f;

#pragma unroll 4
      for (int icl = 0; icl < 64; icl++) {
        float4 a = *(const float4*)&wsA[icl * 64 + ty * 4];
        float4 bb = *(const float4*)&xs[icl * 64 + tx * 4];
        float av[4] = {a.x, a.y, a.z, a.w};
        float bv[4] = {bb.x, bb.y, bb.z, bb.w};
#pragma unroll
        for (int i = 0; i < 4; i++)
#pragma unroll
          for (int j = 0; j < 4; j++) acc[i][j] += av[i] * bv[j];
      }

      float* o = pc + ((size_t)ich * B + b) * CM * HW + t * 64 + tx * 4;
#pragma unroll
      for (int j = 0; j < 4; j++)
        *(float4*)&o[(size_t)(ty * 4 + j) * HW] =
            make_float4(acc[j][0], acc[j][1], acc[j][2], acc[j][3]);
    }
  }

  grid_barrier(&bars[0]);

  // ======================= Phase 1: 3x3 conv ===============================
  for (int vb = bid; vb < 800; vb += NBLK) {
    __syncthreads();                     // protect smem across iterations
    const int t = vb % 50, ocq = (vb / 50) % 4, icq = vb / 200;
    const int ty = t / 10, tx = t - ty * 10;   // tile origin (ty*8, tx*4)
    float* cs   = smem;                  // 1920 floats [bb2][icl16][10*6]
    float* pacc = smem;                  // alias for reduction (3200 floats)

    for (int i = tid; i < 1920; i += 256) {
      int bb = i / 960, r = i - bb * 960;
      int icl = r / 60, rr = r - icl * 60;
      int yy = rr / 6, xx = rr - yy * 6;
      int gy = ty * 8 + yy - 1, gx = tx * 4 + xx - 1;
      float v = 0.f;
      if (gy >= 0 && gy < H && gx >= 0 && gx < W) {
        int o = bb * 102400 + (icq * 16 + icl) * HW + gy * W + gx;
        v = pc[o] + pc[204800 + o] + pc[409600 + o] + pc[614400 + o];
      }
      cs[i] = v;
    }
    __syncthreads();

    const int wv = tid >> 6, lane = tid & 63;
    const int bb = lane >> 5, py = (lane & 31) >> 2, px = lane & 3;
    float acc[25];
#pragma unroll
    for (int j = 0; j < 25; j++) acc[j] = 0.f;

    const float* wbase0 = wT + (size_t)((ocq * 4 + icq) * 16) * 288;  // *9*32

#pragma unroll
    for (int t4 = 0; t4 < 4; t4++) {
      const int icl = __builtin_amdgcn_readfirstlane(wv * 4 + t4);
      const float* c0 = &cs[(bb * 16 + icl) * 60 + py * 6 + px];
      const float* wrow = wbase0 + icl * 288;
#pragma unroll
      for (int dy = 0; dy < 3; dy++)
#pragma unroll
        for (int dx = 0; dx < 3; dx++) {
          const float xv = c0[dy * 6 + dx];
          const float* wq = wrow + (dy * 3 + dx) * 32;
#pragma unroll
          for (int j = 0; j < 25; j++) acc[j] = fmaf(xv, wq[j], acc[j]);
        }
    }

    __syncthreads();
    if (wv == 1 || wv == 3) {
      const int slot = wv >> 1;
#pragma unroll
      for (int j = 0; j < 25; j++) pacc[(slot * 25 + j) * 64 + lane] = acc[j];
    }
    __syncthreads();
    if (wv == 0 || wv == 2) {
      const int slot = wv >> 1;
#pragma unroll
      for (int j = 0; j < 25; j++) acc[j] += pacc[(slot * 25 + j) * 64 + lane];
    }
    __syncthreads();
    if (wv == 2) {
#pragma unroll
      for (int j = 0; j < 25; j++) pacc[j * 64 + lane] = acc[j];
    }
    __syncthreads();
    if (wv == 0) {
      const int base_px = (ty * 8 + py) * W + tx * 4 + px;
#pragma unroll
      for (int ol = 0; ol < 25; ol++)
        encP[(((size_t)icq * 2 + bb) * CE + ocq * 25 + ol) * HW + base_px] =
            acc[ol] + pacc[ol * 64 + lane];
    }
  }

  grid_barrier(&bars[1]);

  // ======================= Phase 2: softmax + reassembly ===================
  for (int vb = bid; vb < 800; vb += NBLK) {
    __syncthreads();                     // protect smem across iterations
    const int i0 = vb % 40, jq = (vb / 40) % 10, b = vb / 400;
    float* xsm  = smem;                  // 10400 floats [px][ch stride 260]
    float* sv   = smem + 10400;          // 400 raw logits [k*16 + v]
    float* wlds = smem + 10800;          // 400 normalized [j0l*100+k*4+d]

    // ---- (a) softmax partial sums, coalesced
    const int t20 = (jq >= 5) ? 1 : 0;
    if (tid < 200) {
      const float* eb = encP + (size_t)b * 160000 + i0 * 40;
#pragma unroll
      for (int u = 0; u < 2; u++) {
        const int p = tid * 2 + u;       // p = k*16 + v
        const int k = p >> 4, v = p & 15;
        const int j0l = v >> 2, d = v & 3;
        const int off = 2 * t20 + (d & 1);
        const int col = (jq * 4 + j0l - 20 * t20) * 2 + (d >> 1);
        const float* ep = eb + (size_t)(k * 4 + off) * 1600 + col;
        sv[p] = ep[0] + ep[320000] + ep[640000] + ep[960000];
      }
    }

    // ---- (b) x halo: 5 rows x 8 cols x 256 ch from padded x
    {
      const float* xb = xpad + (size_t)b * 256 * (44 * 48) + i0 * 48 + jq * 4;
      const int f4 = tid & 1, cth = tid >> 1;    // cth 0..127
#pragma unroll
      for (int it = 0; it < 10; it++) {
        const int ki = (it < 5) ? it : it - 5;
        const int c  = (it < 5 ? 0 : 128) + cth;
        float4 v = *(const float4*)(xb + ((size_t)c * 44 + ki) * 48 + f4 * 4);
        const int px = ki * 8 + f4 * 4;
        xsm[(px + 0) * 260 + c] = v.x;
        xsm[(px + 1) * 260 + c] = v.y;
        xsm[(px + 2) * 260 + c] = v.z;
        xsm[(px + 3) * 260 + c] = v.w;
      }
    }
    __syncthreads();

    // ---- (d) finish softmax: 16 threads, one (j0l,d) variant each
    if (tid < 16) {
      const int j0l = tid >> 2, d = tid & 3;
      float vk[KK];
      float m = -1e30f;
#pragma unroll
      for (int k = 0; k < KK; k++) {
        vk[k] = sv[k * 16 + tid];
        m = fmaxf(m, vk[k]);
      }
      float s = 0.f;
#pragma unroll
      for (int k = 0; k < KK; k++) {
        vk[k] = expf(vk[k] - m);
        s += vk[k];
      }
      const float inv = 1.f / s;
#pragma unroll
      for (int k = 0; k < KK; k++) wlds[j0l * 100 + k * 4 + d] = vk[k] * inv;
    }
    __syncthreads();

    // ---- (f) reassembly compute
    const int wv = tid >> 6, lane = tid & 63, ch0 = lane * 4;
    float4 a0 = make_float4(0.f, 0.f, 0.f, 0.f);
    float4 a1 = a0, a2 = a0, a3 = a0;

#pragma unroll
    for (int ki = 0; ki < 5; ki++)
#pragma unroll
      for (int kj = 0; kj < 5; kj++) {
        float4 xv = *(const float4*)&xsm[(ki * 8 + wv + kj) * 260 + ch0];
        float4 w4 = *(const float4*)&wlds[wv * 100 + (ki * 5 + kj) * 4];
        a0.x += xv.x * w4.x; a0.y += xv.y * w4.x; a0.z += xv.z * w4.x; a0.w += xv.w * w4.x;
        a1.x += xv.x * w4.y; a1.y += xv.y * w4.y; a1.z += xv.z * w4.y; a1.w += xv.w * w4.y;
        a2.x += xv.x * w4.z; a2.y += xv.y * w4.z; a2.z += xv.z * w4.z; a2.w += xv.w * w4.z;
        a3.x += xv.x * w4.w; a3.y += xv.y * w4.w; a3.z += xv.z * w4.w; a3.w += xv.w * w4.w;
      }

    const int j0 = jq * 4 + wv;
    float* ob = out + ((size_t)b * C + ch0) * 6400 + i0 * 160 + j0 * 4;
    *(float4*)&ob[0]     = make_float4(a0.x, a1.x, a2.x, a3.x);
    *(float4*)&ob[6400]  = make_float4(a0.y, a1.y, a2.y, a3.y);
    *(float4*)&ob[12800] = make_float4(a0.z, a1.z, a2.z, a3.z);
    *(float4*)&ob[19200] = make_float4(a0.w, a1.w, a2.w, a3.w);
  }
}

// ---------------------------------------------------------------------------
extern "C" void kernel_launch(void* const* d_in, const int* in_sizes, int n_in,
                              void* d_out, int out_size, void* d_ws, size_t ws_size,
                              hipStream_t stream) {
  const float* x      = (const float*)d_in[0];
  const float* w_comp = (const float*)d_in[1];
  const float* w_enc  = (const float*)d_in[2];
  float* out = (float*)d_out;

  float* pc       = (float*)d_ws;                      // 3,276,800 B
  float* encP     = (float*)((char*)d_ws + 3276800);   // 5,120,000 B
  float* wT       = (float*)((char*)d_ws + 8396800);   //   294,912 B
  float* xpad     = (float*)((char*)d_ws + 8691712);   // 4,325,376 B
  unsigned* bars  = (unsigned*)((char*)d_ws + 16000000);  // 2 counters

  // counters are poisoned by the harness each iteration -> re-zero (capturable)
  hipMemsetAsync(bars, 0, 2 * sizeof(unsigned), stream);

  k_all<<<dim3(NBLK), dim3(256), 0, stream>>>(x, w_comp, w_enc, pc, encP, wT,
                                              xpad, out, bars);
}

// Round 7
// 102.865 us; speedup vs baseline: 2.6066x; 1.9276x over previous
//
#include <hip/hip_runtime.h>

#define B   2
#define C   256
#define CM  64     // compressed channels
#define CE  100    // encoder out channels
#define H   40
#define W   40
#define HW  1600
#define KK  25     // K*K

// ---------------------------------------------------------------------------
// K1 (fused prep + 1x1 conv), one launch, 937 blocks:
//   blocks   0..199 : 1x1 conv 256->64 LDS GEMM (25 px-tiles, 4 K-quarters, 2 b)
//   blocks 200..711 : zero-pad x -> xpad[b][c][44][48]
//   blocks 712..936 : transpose w_enc -> wT[((ocq*4+icq)*16+icl)*9+tap][32]
// ---------------------------------------------------------------------------
__global__ __launch_bounds__(256) void k1_fused(
    const float* __restrict__ x, const float* __restrict__ w_comp,
    const float* __restrict__ w_enc, float* __restrict__ pc,
    float* __restrict__ xpad, float* __restrict__ wT) {
  const int bid = blockIdx.x;
  const int tid = threadIdx.x;

  if (bid >= 712) {                      // ---- weight transpose (57600 elems)
    int idx = (bid - 712) * 256 + tid;
    if (idx < 57600) {
      int row = idx / 576, col = idx - row * 576;  // col = (icq*16+icl)*9+tap
      int ocq = row / 25, ol = row - ocq * 25;
      wT[((size_t)(ocq * 576 + col)) * 32 + ol] = w_enc[idx];
    }
    return;
  }
  if (bid >= 200) {                      // ---- pad one (b,c) plane of x
    const int plane = bid - 200;         // 0..511
    const float* src = x + (size_t)plane * HW;
    float* dst = xpad + (size_t)plane * (44 * 48);
    for (int i = tid; i < 44 * 48; i += 256) {
      int py = i / 48, px = i - py * 48;
      int gy = py - 2, gx = px - 2;
      float v = 0.f;
      if (gy >= 0 && gy < H && gx >= 0 && gx < W) v = src[gy * W + gx];
      dst[i] = v;
    }
    return;
  }

  // ---- 1x1 conv GEMM (identical to proven k1)
  const int t = bid % 25, ich = (bid / 25) & 3, b = bid / 100;
  __shared__ __align__(16) float xs[64 * 64];    // 16 KB [icl][px]
  __shared__ __align__(16) float wsA[64 * 64];   // 16 KB [icl][oc]

  const float4* x4 = (const float4*)(x + ((size_t)b * C + ich * 64) * HW + t * 64);
#pragma unroll
  for (int i = 0; i < 4; i++) {
    int idx = tid + i * 256;                     // icl = idx>>4, q = idx&15
    ((float4*)xs)[idx] = x4[(idx >> 4) * 400 + (idx & 15)];
  }
  const float4* w4 = (const float4*)w_comp;
#pragma unroll
  for (int i = 0; i < 4; i++) {
    int idx = tid + i * 256;
    int icq = idx >> 6, oc = idx & 63;           // icq 0..15
    float4 f = w4[oc * 64 + ich * 16 + icq];
    wsA[(icq * 4 + 0) * 64 + oc] = f.x;
    wsA[(icq * 4 + 1) * 64 + oc] = f.y;
    wsA[(icq * 4 + 2) * 64 + oc] = f.z;
    wsA[(icq * 4 + 3) * 64 + oc] = f.w;
  }
  __syncthreads();

  const int ty = tid >> 4, tx = tid & 15;
  float acc[4][4];
#pragma unroll
  for (int i = 0; i < 4; i++)
#pragma unroll
    for (int j = 0; j < 4; j++) acc[i][j] = 0.f;

#pragma unroll 4
  for (int icl = 0; icl < 64; icl++) {
    float4 a = *(const float4*)&wsA[icl * 64 + ty * 4];
    float4 bb = *(const float4*)&xs[icl * 64 + tx * 4];
    float av[4] = {a.x, a.y, a.z, a.w};
    float bv[4] = {bb.x, bb.y, bb.z, bb.w};
#pragma unroll
    for (int i = 0; i < 4; i++)
#pragma unroll
      for (int j = 0; j < 4; j++) acc[i][j] += av[i] * bv[j];
  }

  float* o = pc + ((size_t)ich * B + b) * CM * HW + t * 64 + tx * 4;
#pragma unroll
  for (int j = 0; j < 4; j++)
    *(float4*)&o[(size_t)(ty * 4 + j) * HW] =
        make_float4(acc[j][0], acc[j][1], acc[j][2], acc[j][3]);
}

// ---------------------------------------------------------------------------
// K2: 3x3 conv 64 -> 100, pad 1.  grid (50 tiles of 8x4 px, 4 ocq, 4 icq)
// = 800 blocks. Lane = (bb, 8x4 px); 4 waves k-split 16 ic (4 each).
// Weights via wave-uniform scalar loads from wT -> LDS inner loop is a
// single ds_read_b32 per tap. Cross-wave tree-reduce via aliased LDS.
// ---------------------------------------------------------------------------
__global__ __launch_bounds__(256) void k2_conv3x3(
    const float* __restrict__ pc, const float* __restrict__ wT,
    float* __restrict__ encP) {
  const int t = blockIdx.x, ocq = blockIdx.y, icq = blockIdx.z;
  const int ty = t / 10, tx = t - ty * 10;       // tile origin (ty*8, tx*4)
  __shared__ __align__(16) float smem[3200];     // 12.8 KB
  float* cs   = smem;    // [bb2][icl16][10*6 halo] = 1920 floats
  float* pacc = smem;    // alias for reduction (3200 floats)
  const int tid = threadIdx.x;

  for (int i = tid; i < 1920; i += 256) {
    int bb = i / 960, r = i - bb * 960;
    int icl = r / 60, rr = r - icl * 60;
    int yy = rr / 6, xx = rr - yy * 6;
    int gy = ty * 8 + yy - 1, gx = tx * 4 + xx - 1;
    float v = 0.f;
    if (gy >= 0 && gy < H && gx >= 0 && gx < W) {
      int o = bb * 102400 + (icq * 16 + icl) * HW + gy * W + gx;
      v = pc[o] + pc[204800 + o] + pc[409600 + o] + pc[614400 + o];
    }
    cs[i] = v;
  }
  __syncthreads();

  const int wv = tid >> 6, lane = tid & 63;
  const int bb = lane >> 5, py = (lane & 31) >> 2, px = lane & 3;
  float acc[25];
#pragma unroll
  for (int j = 0; j < 25; j++) acc[j] = 0.f;

  const float* wbase0 = wT + (size_t)((ocq * 4 + icq) * 16) * 288;  // *9*32

#pragma unroll
  for (int t4 = 0; t4 < 4; t4++) {
    const int icl = __builtin_amdgcn_readfirstlane(wv * 4 + t4);
    const float* c0 = &cs[(bb * 16 + icl) * 60 + py * 6 + px];
    const float* wrow = wbase0 + icl * 288;
#pragma unroll
    for (int dy = 0; dy < 3; dy++)
#pragma unroll
      for (int dx = 0; dx < 3; dx++) {
        const float xv = c0[dy * 6 + dx];
        const float* wq = wrow + (dy * 3 + dx) * 32;
#pragma unroll
        for (int j = 0; j < 25; j++) acc[j] = fmaf(xv, wq[j], acc[j]);
      }
  }

  __syncthreads();
  if (wv == 1 || wv == 3) {
    const int slot = wv >> 1;
#pragma unroll
    for (int j = 0; j < 25; j++) pacc[(slot * 25 + j) * 64 + lane] = acc[j];
  }
  __syncthreads();
  if (wv == 0 || wv == 2) {
    const int slot = wv >> 1;
#pragma unroll
    for (int j = 0; j < 25; j++) acc[j] += pacc[(slot * 25 + j) * 64 + lane];
  }
  __syncthreads();
  if (wv == 2) {
#pragma unroll
    for (int j = 0; j < 25; j++) pacc[j * 64 + lane] = acc[j];
  }
  __syncthreads();
  if (wv == 0) {
    const int base_px = (ty * 8 + py) * W + tx * 4 + px;
#pragma unroll
    for (int ol = 0; ol < 25; ol++)
      encP[(((size_t)icq * 2 + bb) * CE + ocq * 25 + ol) * HW + base_px] =
          acc[ol] + pacc[ol * 64 + lane];
  }
}

// ---------------------------------------------------------------------------
// K3 (fused softmax + reassembly). grid (40 i0, 10 jq, 2 b) = 800 blocks.
// Phase a: 200 threads coalesced-load the 400 (variant,k) encP sums -> sv.
// Phase b: all threads stage x halo from xpad (float4, conflict-free scatter).
// Phase d: 16 threads finish softmax (max/exp/norm, all LDS) -> wlds.
// Phase f: per tap one b128 x-read + one b128 w-broadcast -> 16 FMAs.
// ---------------------------------------------------------------------------
__global__ __launch_bounds__(256) void k3_fused(
    const float* __restrict__ xpad, const float* __restrict__ encP,
    float* __restrict__ out) {
  const int i0 = blockIdx.x;
  const int jq = blockIdx.y;
  const int b  = blockIdx.z;
  const int tid = threadIdx.x;

  __shared__ __align__(16) float xsm[40 * 260];  // 40.6 KB
  __shared__ __align__(16) float sv[400];        // raw logits [k*16 + v]
  __shared__ __align__(16) float wlds[400];      // normalized [j0l*100+k*4+d]

  // ---- (a) softmax partial sums, coalesced (2 (variant,k) pairs per thread)
  const int t20 = (jq >= 5) ? 1 : 0;
  if (tid < 200) {
    const float* eb = encP + (size_t)b * 160000 + i0 * 40;
#pragma unroll
    for (int u = 0; u < 2; u++) {
      const int p = tid * 2 + u;                 // p = k*16 + v
      const int k = p >> 4, v = p & 15;
      const int j0l = v >> 2, d = v & 3;
      const int off = 2 * t20 + (d & 1);
      const int col = (jq * 4 + j0l - 20 * t20) * 2 + (d >> 1);
      const float* ep = eb + (size_t)(k * 4 + off) * 1600 + col;
      sv[p] = ep[0] + ep[320000] + ep[640000] + ep[960000];
    }
  }

  // ---- (b) x halo: 5 rows x 8 cols x 256 ch from padded x
  {
    const float* xb = xpad + (size_t)b * 256 * (44 * 48) + i0 * 48 + jq * 4;
    const int f4 = tid & 1, cth = tid >> 1;      // cth 0..127
#pragma unroll
    for (int it = 0; it < 10; it++) {
      const int ki = (it < 5) ? it : it - 5;
      const int c  = (it < 5 ? 0 : 128) + cth;
      float4 v = *(const float4*)(xb + ((size_t)c * 44 + ki) * 48 + f4 * 4);
      const int px = ki * 8 + f4 * 4;
      xsm[(px + 0) * 260 + c] = v.x;
      xsm[(px + 1) * 260 + c] = v.y;
      xsm[(px + 2) * 260 + c] = v.z;
      xsm[(px + 3) * 260 + c] = v.w;
    }
  }
  __syncthreads();

  // ---- (d) finish softmax: 16 threads, one (j0l,d) variant each, all in LDS
  if (tid < 16) {
    const int j0l = tid >> 2, d = tid & 3;
    float vk[KK];
    float m = -1e30f;
#pragma unroll
    for (int k = 0; k < KK; k++) {
      vk[k] = sv[k * 16 + tid];
      m = fmaxf(m, vk[k]);
    }
    float s = 0.f;
#pragma unroll
    for (int k = 0; k < KK; k++) {
      vk[k] = expf(vk[k] - m);
      s += vk[k];
    }
    const float inv = 1.f / s;
#pragma unroll
    for (int k = 0; k < KK; k++) wlds[j0l * 100 + k * 4 + d] = vk[k] * inv;
  }
  __syncthreads();

  // ---- (f) reassembly compute
  const int wv = tid >> 6, lane = tid & 63, ch0 = lane * 4;
  float4 a0 = make_float4(0.f, 0.f, 0.f, 0.f);
  float4 a1 = a0, a2 = a0, a3 = a0;

#pragma unroll
  for (int ki = 0; ki < 5; ki++)
#pragma unroll
    for (int kj = 0; kj < 5; kj++) {
      float4 xv = *(const float4*)&xsm[(ki * 8 + wv + kj) * 260 + ch0];
      float4 w4 = *(const float4*)&wlds[wv * 100 + (ki * 5 + kj) * 4];
      a0.x += xv.x * w4.x; a0.y += xv.y * w4.x; a0.z += xv.z * w4.x; a0.w += xv.w * w4.x;
      a1.x += xv.x * w4.y; a1.y += xv.y * w4.y; a1.z += xv.z * w4.y; a1.w += xv.w * w4.y;
      a2.x += xv.x * w4.z; a2.y += xv.y * w4.z; a2.z += xv.z * w4.z; a2.w += xv.w * w4.z;
      a3.x += xv.x * w4.w; a3.y += xv.y * w4.w; a3.z += xv.z * w4.w; a3.w += xv.w * w4.w;
    }

  const int j0 = jq * 4 + wv;
  float* ob = out + ((size_t)b * C + ch0) * 6400 + i0 * 160 + j0 * 4;
  *(float4*)&ob[0]     = make_float4(a0.x, a1.x, a2.x, a3.x);
  *(float4*)&ob[6400]  = make_float4(a0.y, a1.y, a2.y, a3.y);
  *(float4*)&ob[12800] = make_float4(a0.z, a1.z, a2.z, a3.z);
  *(float4*)&ob[19200] = make_float4(a0.w, a1.w, a2.w, a3.w);
}

// ---------------------------------------------------------------------------
extern "C" void kernel_launch(void* const* d_in, const int* in_sizes, int n_in,
                              void* d_out, int out_size, void* d_ws, size_t ws_size,
                              hipStream_t stream) {
  const float* x      = (const float*)d_in[0];
  const float* w_comp = (const float*)d_in[1];
  const float* w_enc  = (const float*)d_in[2];
  float* out = (float*)d_out;

  float* pc    = (float*)d_ws;                       // 3,276,800 B
  float* encP  = (float*)((char*)d_ws + 3276800);    // 5,120,000 B
  float* wT    = (float*)((char*)d_ws + 8396800);    //   294,912 B
  float* xpad  = (float*)((char*)d_ws + 8691712);    // 4,325,376 B

  k1_fused<<<dim3(937), 256, 0, stream>>>(x, w_comp, w_enc, pc, xpad, wT);
  k2_conv3x3<<<dim3(50, 4, 4), 256, 0, stream>>>(pc, wT, encP);
  k3_fused<<<dim3(40, 10, B), 256, 0, stream>>>(xpad, encP, out);
}